// Round 1
// baseline (6411.212 us; speedup 1.0000x reference)
//
#include <hip/hip_runtime.h>
#include <hip/hip_bf16.h>
#include <stdint.h>

#define EPSV 1e-12f
#define NB 32
#define DD 1024
#define QQ 64
#define EE 384
#define HH 384
#define NW 12   // workgroups per (corpus,dir) recurrence group

typedef __attribute__((ext_vector_type(4))) float f32x4;
typedef __attribute__((ext_vector_type(8))) __bf16 bf16x8;
typedef __attribute__((ext_vector_type(4))) unsigned short u16x4;
typedef unsigned short u16;

static __device__ __forceinline__ u16 f2bf(float f) {
  union { float f; uint32_t u; } v; v.f = f;
  uint32_t u = v.u;
  return (u16)((u + 0x7fffu + ((u >> 16) & 1u)) >> 16);  // RNE
}

static __device__ __forceinline__ f32x4 MFMA(bf16x8 a, bf16x8 b, f32x4 c) {
  return __builtin_amdgcn_mfma_f32_16x16x32_bf16(a, b, c, 0, 0, 0);
}

// ---------------- embedding gather: emb_x[row][e] = bf16(emb[token[row]][e]) ----------------
__global__ __launch_bounds__(256) void k_emb(const int* __restrict__ doc, const int* __restrict__ qry,
                                             const float* __restrict__ emb, u16* __restrict__ embx) {
  int i = blockIdx.x * 256 + threadIdx.x;          // 34816*96 tasks (float4 granules)
  int row = i / 96, e4 = i - row * 96;
  int tok = (row < NB * DD) ? doc[row] : qry[row - NB * DD];
  float4 v = ((const float4*)(emb + (size_t)tok * EE))[e4];
  u16x4 o; o.x = f2bf(v.x); o.y = f2bf(v.y); o.z = f2bf(v.z); o.w = f2bf(v.w);
  *(u16x4*)(embx + (size_t)row * EE + e4 * 4) = o;
}

// ---------------- group barrier: release count, relaxed spin, acquire ----------------
static __device__ __forceinline__ void grpbar(unsigned* c) {
  __syncthreads();
  if (threadIdx.x == 0) {
    __hip_atomic_fetch_add(c, 1u, __ATOMIC_RELEASE, __HIP_MEMORY_SCOPE_AGENT);
    while (__hip_atomic_load(c, __ATOMIC_RELAXED, __HIP_MEMORY_SCOPE_AGENT) < (unsigned)NW)
      __builtin_amdgcn_s_sleep(2);
    (void)__hip_atomic_load(c, __ATOMIC_ACQUIRE, __HIP_MEMORY_SCOPE_AGENT);
  }
  __syncthreads();
}

// ---------------- fused BiGRU recurrence ----------------
// grid = 4 groups (doc_f, doc_b, q_f, q_b) x NW.  Each WG owns 32 hidden dims,
// holds its [96 rows x 768 K] bf16 weight slice ([W_ih | W_hh]) in LDS as MFMA B-fragments,
// processes all 32 batches. h broadcast via global bf16 ping-pong + per-step barrier.
__global__ __launch_bounds__(256) void k_rec(
    const u16* __restrict__ embx,
    const int* __restrict__ doc_lens, const int* __restrict__ q_lens,
    const float* __restrict__ w_ih_f, const float* __restrict__ w_hh_f,
    const float* __restrict__ b_ih_f, const float* __restrict__ b_hh_f,
    const float* __restrict__ w_ih_b, const float* __restrict__ w_hh_b,
    const float* __restrict__ b_ih_b, const float* __restrict__ b_hh_b,
    u16* __restrict__ doc_h, u16* __restrict__ q_h,
    u16* __restrict__ h_bc, unsigned* __restrict__ cnts) {
  __shared__ u16 wfrag[73728];       // 6 n-tiles x 24 k-steps x 64 lanes x 8 bf16 = 147456 B
  __shared__ float h_own[32][33];    // this WG's f32 state slice [batch][local dim]
  __shared__ int lensh[32];

  const int grp = blockIdx.x / NW;
  const int wg = blockIdx.x - grp * NW;
  const int corpus = grp >> 1, dir = grp & 1;
  const int T = corpus ? QQ : DD;
  const int* lens = corpus ? q_lens : doc_lens;
  const float* w_ih = dir ? w_ih_b : w_ih_f;
  const float* w_hh = dir ? w_hh_b : w_hh_f;
  const float* b_ih = dir ? b_ih_b : b_ih_f;
  const float* b_hh = dir ? b_hh_b : b_hh_f;
  u16* out = corpus ? q_h : doc_h;
  const u16* ex_base = embx + (corpus ? (size_t)NB * DD * EE : 0);
  u16* hb = h_bc + (size_t)grp * (2 * NB * HH);
  unsigned* cnt = cnts + grp * 1056;
  const int tid = threadIdx.x;

  if (tid < 32) lensh[tid] = lens[tid];
  // pack weight slice into per-fragment LDS layout (lane-linear, conflict-free reads)
  for (int idx = tid; idx < 73728; idx += 256) {
    int nt = idx / 12288;
    int rem = idx - nt * 12288;
    int ks = rem >> 9;
    int le = rem & 511;
    int lane_ = le >> 3, i = le & 7;
    int g = nt >> 1, js_ = nt & 1;
    int colw = lane_ & 15, khiw = lane_ >> 4;
    int k = ks * 32 + khiw * 8 + i;
    int rowg = g * 384 + wg * 32 + js_ * 16 + colw;
    float v = (k < 384) ? w_ih[rowg * 384 + k] : w_hh[rowg * 384 + (k - 384)];
    wfrag[idx] = f2bf(v);
  }
  for (int idx = tid; idx < 32 * 33; idx += 256) (&h_own[0][0])[idx] = 0.f;
  for (int idx = tid; idx < 1024; idx += 256) {   // zero own slice of broadcast buf 0
    int b = idx >> 5, jl_ = idx & 31;
    hb[b * HH + wg * 32 + jl_] = 0;
  }
  grpbar(cnt + 0);

  const int lane = tid & 63, wv = tid >> 6;
  const int mt = wv >> 1, js = wv & 1;
  const int col = lane & 15, khi = lane >> 4;
  const int jg = wg * 32 + js * 16 + col;          // hidden dim this lane produces
  const float bias_r = b_ih[jg] + b_hh[jg];
  const float bias_z = b_ih[384 + jg] + b_hh[384 + jg];
  const float bias_in = b_ih[768 + jg];
  const float bias_hn = b_hh[768 + jg];
  const int b_x = mt * 16 + col;                   // A-fragment batch row
  const int len_x = lensh[b_x];
  const int bh0 = mt * 16 + khi * 4;               // accumulator batch base
  int len_h[4];
#pragma unroll
  for (int r = 0; r < 4; ++r) len_h[r] = lensh[bh0 + r];
  const u16* exrow = ex_base + (size_t)b_x * T * EE + khi * 8;
  u16* outp = out + (size_t)dir * HH + jg;
  const int jl = js * 16 + col;

  auto trow_of = [&](int s) -> int { return dir ? ((s < len_x) ? (len_x - 1 - s) : s) : s; };
  auto load_ax = [&](bf16x8* ax, int s) {
    const u16* axp = exrow + (size_t)trow_of(s) * EE;
#pragma unroll
    for (int ks = 0; ks < 12; ++ks) ax[ks] = *(const bf16x8*)(axp + ks * 32);
  };

  bf16x8 axA[12], axB[12];
  load_ax(axA, 0);

  auto step = [&](int s, bf16x8* axc, bf16x8* axn) {
    const int p = s & 1;
    const u16* rbuf = hb + p * (NB * HH);
    u16* wbuf = hb + (p ^ 1) * (NB * HH);
    const u16* ahp = rbuf + b_x * HH + khi * 8;
    bf16x8 ah[12];
#pragma unroll
    for (int ks = 0; ks < 12; ++ks) ah[ks] = *(const bf16x8*)(ahp + ks * 32);
    f32x4 acc_r{0.f, 0.f, 0.f, 0.f};
    f32x4 acc_z = acc_r, acc_nx = acc_r, acc_nh = acc_r;
#pragma unroll
    for (int ks = 0; ks < 12; ++ks) {   // x-part (K 0..383)
      bf16x8 br = *(const bf16x8*)&wfrag[((js) * 24 + ks) * 512 + lane * 8];
      bf16x8 bz = *(const bf16x8*)&wfrag[((2 + js) * 24 + ks) * 512 + lane * 8];
      bf16x8 bn = *(const bf16x8*)&wfrag[((4 + js) * 24 + ks) * 512 + lane * 8];
      acc_r = MFMA(axc[ks], br, acc_r);
      acc_z = MFMA(axc[ks], bz, acc_z);
      acc_nx = MFMA(axc[ks], bn, acc_nx);
    }
#pragma unroll
    for (int ks = 0; ks < 12; ++ks) {   // h-part (K 384..767)
      bf16x8 br = *(const bf16x8*)&wfrag[((js) * 24 + 12 + ks) * 512 + lane * 8];
      bf16x8 bz = *(const bf16x8*)&wfrag[((2 + js) * 24 + 12 + ks) * 512 + lane * 8];
      bf16x8 bn = *(const bf16x8*)&wfrag[((4 + js) * 24 + 12 + ks) * 512 + lane * 8];
      acc_r = MFMA(ah[ks], br, acc_r);
      acc_z = MFMA(ah[ks], bz, acc_z);
      acc_nh = MFMA(ah[ks], bn, acc_nh);
    }
#pragma unroll
    for (int r = 0; r < 4; ++r) {
      const int b = bh0 + r;
      float rg = 1.f / (1.f + __expf(-(acc_r[r] + bias_r)));
      float zg = 1.f / (1.f + __expf(-(acc_z[r] + bias_z)));
      float ng = tanhf(acc_nx[r] + bias_in + rg * (acc_nh[r] + bias_hn));
      float hp = h_own[b][jl];
      float hn = (1.f - zg) * ng + zg * hp;
      h_own[b][jl] = hn;
      u16 hq = f2bf(hn);
      wbuf[b * HH + jg] = hq;
      const int len = len_h[r];
      const int tro = dir ? ((s < len) ? (len - 1 - s) : s) : s;
      outp[((size_t)b * T + tro) * (2 * HH)] = hq;
    }
    if (s + 1 < T) load_ax(axn, s + 1);   // prefetch next x (overlaps barrier)
    grpbar(cnt + 1 + s);
  };

  for (int s = 0; s < T; s += 2) {
    step(s, axA, axB);
    step(s + 1, axB, axA);
  }
}

// ---------------- scores + row (q-axis) stats, MFMA, one WG per (b, 64-row d block) ----------------
__global__ __launch_bounds__(256) void k_scores(
    const u16* __restrict__ doc_h, const u16* __restrict__ q_h,
    const int* __restrict__ doc_lens, const int* __restrict__ q_lens,
    float* __restrict__ SM, float* __restrict__ rowmax, float* __restrict__ rowsum) {
  const int b = blockIdx.x >> 4, dblk = blockIdx.x & 15;
  const int tid = threadIdx.x, lane = tid & 63, wv = tid >> 6;
  const int col = lane & 15, khi = lane >> 4;
  const int dlen = doc_lens[b], qlen = q_lens[b];
  const u16* dp = doc_h + ((size_t)(b * DD + dblk * 64 + wv * 16 + col)) * (2 * HH) + khi * 8;
  const u16* qp = q_h + (size_t)b * QQ * (2 * HH);
  f32x4 acc[4];
#pragma unroll
  for (int nt = 0; nt < 4; ++nt) acc[nt] = f32x4{0.f, 0.f, 0.f, 0.f};
  for (int ks = 0; ks < 24; ++ks) {
    bf16x8 av = *(const bf16x8*)(dp + ks * 32);
#pragma unroll
    for (int nt = 0; nt < 4; ++nt) {
      bf16x8 bv = *(const bf16x8*)(qp + (size_t)(nt * 16 + col) * (2 * HH) + ks * 32 + khi * 8);
      acc[nt] = MFMA(av, bv, acc[nt]);
    }
  }
  const int d0 = dblk * 64 + wv * 16 + khi * 4;
  float* smb = SM + (size_t)b * DD * QQ;
#pragma unroll
  for (int r = 0; r < 4; ++r) {
    const int d = d0 + r;
    const bool dv = d < dlen;
    float v[4];
#pragma unroll
    for (int nt = 0; nt < 4; ++nt) {
      const int q = nt * 16 + col;
      v[nt] = (dv && q < qlen) ? acc[nt][r] : 0.f;   // exact zeros at masked pairs (ref semantics)
      smb[(size_t)d * QQ + q] = v[nt];
    }
    float mx = fmaxf(fmaxf(v[0], v[1]), fmaxf(v[2], v[3]));
#pragma unroll
    for (int off = 1; off < 16; off <<= 1) mx = fmaxf(mx, __shfl_xor(mx, off, 64));
    float sm = 0.f;
#pragma unroll
    for (int nt = 0; nt < 4; ++nt) {
      const int q = nt * 16 + col;
      if (dv && q < qlen) sm += __expf(v[nt] - mx);
    }
#pragma unroll
    for (int off = 1; off < 16; off <<= 1) sm += __shfl_xor(sm, off, 64);
    if (col == 0) { rowmax[b * DD + d] = mx; rowsum[b * DD + d] = sm; }
  }
}

// ---------------- column (d-axis) stats + beta_aver, one WG per batch ----------------
__global__ __launch_bounds__(256) void k_cols(
    const float* __restrict__ SM, const float* __restrict__ rowmax, const float* __restrict__ rowsum,
    const int* __restrict__ doc_lens, const int* __restrict__ q_lens,
    float* __restrict__ colmax, float* __restrict__ colsum, float* __restrict__ bav) {
  const int b = blockIdx.x, tid = threadIdx.x;
  const int q = tid & 63, dg = tid >> 6;
  __shared__ float red[4][64];
  __shared__ float cmx[64];
  const float* smb = SM + (size_t)b * DD * QQ;
  float cm = -3.0e38f;
  for (int d = dg; d < DD; d += 4) cm = fmaxf(cm, smb[(size_t)d * QQ + q]);
  red[dg][q] = cm;
  __syncthreads();
  if (tid < 64) cmx[tid] = fmaxf(fmaxf(red[0][tid], red[1][tid]), fmaxf(red[2][tid], red[3][tid]));
  __syncthreads();
  const int dlen = doc_lens[b];
  const bool qv = q < q_lens[b];
  const float cmq = cmx[q];
  float cs = 0.f, ba = 0.f;
  for (int d = dg; d < DD; d += 4) {
    if (qv && d < dlen) {
      float v = smb[(size_t)d * QQ + q];
      cs += __expf(v - cmq);
      ba += __expf(v - rowmax[b * DD + d]) / (rowsum[b * DD + d] + EPSV);
    }
  }
  __syncthreads();
  red[dg][q] = cs;
  __syncthreads();
  float cst = 0.f;
  if (tid < 64) cst = red[0][tid] + red[1][tid] + red[2][tid] + red[3][tid];
  __syncthreads();
  red[dg][q] = ba;
  __syncthreads();
  if (tid < 64) {
    float bat = red[0][tid] + red[1][tid] + red[2][tid] + red[3][tid];
    colmax[b * QQ + tid] = cmx[tid];
    colsum[b * QQ + tid] = cst;
    bav[b * QQ + tid] = bat / (float)dlen;
  }
}

// ---------------- s = alpha @ beta_aver, probs, vocab scatter ----------------
__global__ __launch_bounds__(256) void k_s(
    const float* __restrict__ SM, const float* __restrict__ colmax, const float* __restrict__ colsum,
    const float* __restrict__ bav, const int* __restrict__ doc_lens, const int* __restrict__ q_lens,
    const int* __restrict__ documents, const int* __restrict__ answers,
    float* __restrict__ sc, float* __restrict__ cnt_tok, float* __restrict__ dout) {
  const int b = blockIdx.x >> 2, dblk = blockIdx.x & 3;
  const int tid = threadIdx.x;
  __shared__ float cm[64], cs[64], bv[64];
  __shared__ int qm[64];
  if (tid < 64) {
    cm[tid] = colmax[b * QQ + tid];
    cs[tid] = colsum[b * QQ + tid];
    bv[tid] = bav[b * QQ + tid];
    qm[tid] = (tid < q_lens[b]) ? 1 : 0;
  }
  __syncthreads();
  const int d = dblk * 256 + tid;
  const bool dv = d < doc_lens[b];
  const float* smr = SM + ((size_t)b * DD + d) * QQ;
  float sd = 0.f;
#pragma unroll
  for (int q = 0; q < 64; ++q) {
    float e = (dv && qm[q]) ? __expf(smr[q] - cm[q]) : 0.f;
    sd += e / (cs[q] + EPSV) * bv[q];
  }
  const int tok = documents[b * DD + d];
  if (tok == answers[b]) atomicAdd(&dout[b], sd);
  if (dv) {
    atomicAdd(&sc[(size_t)b * 50001 + tok], sd);
    atomicAdd(&cnt_tok[(size_t)b * 50001 + tok], 1.0f);
  }
}

// ---------------- first-max argmax over vocab, one WG per batch ----------------
__global__ __launch_bounds__(256) void k_pred(
    const float* __restrict__ sc, const float* __restrict__ cnt_tok, float* __restrict__ dout) {
  const int b = blockIdx.x, tid = threadIdx.x;
  __shared__ float bvs[256];
  __shared__ int bis[256];
  float bvv = -3.0e38f;
  int bii = 0x7fffffff;
  for (int i = tid; i < 50001; i += 256) {
    if (cnt_tok[(size_t)b * 50001 + i] > 0.f) {
      float v = sc[(size_t)b * 50001 + i];
      if (v > bvv) { bvv = v; bii = i; }   // i increasing -> keeps first index per thread
    }
  }
  bvs[tid] = bvv;
  bis[tid] = bii;
  __syncthreads();
  for (int st = 128; st > 0; st >>= 1) {
    if (tid < st) {
      float v2 = bvs[tid + st];
      int i2 = bis[tid + st];
      if (v2 > bvs[tid] || (v2 == bvs[tid] && i2 < bis[tid])) { bvs[tid] = v2; bis[tid] = i2; }
    }
    __syncthreads();
  }
  if (tid == 0) dout[32 + b] = (float)bis[0];
}

extern "C" void kernel_launch(void* const* d_in, const int* in_sizes, int n_in,
                              void* d_out, int out_size, void* d_ws, size_t ws_size,
                              hipStream_t stream) {
  const int* documents = (const int*)d_in[0];
  const int* doc_lens = (const int*)d_in[1];
  const int* querys = (const int*)d_in[3];
  const int* query_lens = (const int*)d_in[4];
  const int* answers = (const int*)d_in[6];
  const float* emb = (const float*)d_in[7];
  const float* w_ih_f = (const float*)d_in[8];
  const float* w_hh_f = (const float*)d_in[9];
  const float* b_ih_f = (const float*)d_in[10];
  const float* b_hh_f = (const float*)d_in[11];
  const float* w_ih_b = (const float*)d_in[12];
  const float* w_hh_b = (const float*)d_in[13];
  const float* b_ih_b = (const float*)d_in[14];
  const float* b_hh_b = (const float*)d_in[15];
  float* dout = (float*)d_out;
  char* ws = (char*)d_ws;

  size_t o = 0;
  auto alloc = [&](size_t bytes) { size_t r = o; o += (bytes + 255) & ~(size_t)255; return r; };
  size_t o_embx = alloc((size_t)34816 * 384 * 2);
  size_t o_doch = alloc((size_t)NB * DD * 768 * 2);
  size_t o_qh   = alloc((size_t)NB * QQ * 768 * 2);
  size_t o_hbc  = alloc((size_t)4 * 2 * NB * HH * 2);
  size_t o_cnt  = alloc((size_t)4 * 1056 * 4);
  size_t o_SM   = alloc((size_t)NB * DD * QQ * 4);
  size_t o_rmax = alloc((size_t)NB * DD * 4);
  size_t o_rsum = alloc((size_t)NB * DD * 4);
  size_t o_cmax = alloc((size_t)NB * QQ * 4);
  size_t o_csum = alloc((size_t)NB * QQ * 4);
  size_t o_bav  = alloc((size_t)NB * QQ * 4);
  size_t o_sc   = alloc((size_t)NB * 50001 * 4);
  size_t o_ctk  = alloc((size_t)NB * 50001 * 4);
  (void)ws_size; (void)in_sizes; (void)n_in; (void)out_size;

  hipMemsetAsync(ws + o_cnt, 0, (size_t)4 * 1056 * 4, stream);
  hipMemsetAsync(ws + o_sc, 0, (o_ctk - o_sc) + (size_t)NB * 50001 * 4, stream);
  hipMemsetAsync(d_out, 0, 64 * sizeof(float), stream);

  k_emb<<<13056, 256, 0, stream>>>(documents, querys, emb, (u16*)(ws + o_embx));
  k_rec<<<48, 256, 0, stream>>>((u16*)(ws + o_embx), doc_lens, query_lens,
                                w_ih_f, w_hh_f, b_ih_f, b_hh_f,
                                w_ih_b, w_hh_b, b_ih_b, b_hh_b,
                                (u16*)(ws + o_doch), (u16*)(ws + o_qh),
                                (u16*)(ws + o_hbc), (unsigned*)(ws + o_cnt));
  k_scores<<<512, 256, 0, stream>>>((u16*)(ws + o_doch), (u16*)(ws + o_qh), doc_lens, query_lens,
                                    (float*)(ws + o_SM), (float*)(ws + o_rmax), (float*)(ws + o_rsum));
  k_cols<<<32, 256, 0, stream>>>((float*)(ws + o_SM), (float*)(ws + o_rmax), (float*)(ws + o_rsum),
                                 doc_lens, query_lens,
                                 (float*)(ws + o_cmax), (float*)(ws + o_csum), (float*)(ws + o_bav));
  k_s<<<128, 256, 0, stream>>>((float*)(ws + o_SM), (float*)(ws + o_cmax), (float*)(ws + o_csum),
                               (float*)(ws + o_bav), doc_lens, query_lens, documents, answers,
                               (float*)(ws + o_sc), (float*)(ws + o_ctk), dout);
  k_pred<<<32, 256, 0, stream>>>((float*)(ws + o_sc), (float*)(ws + o_ctk), dout);
}

// Round 3
// 5999.981 us; speedup vs baseline: 1.0685x; 1.0685x over previous
//
#include <hip/hip_runtime.h>
#include <hip/hip_bf16.h>
#include <stdint.h>

#define EPSV 1e-12f
#define NB 32
#define DD 1024
#define QQ 64
#define EE 384
#define HH 384
#define NW 12   // workgroups per (corpus,dir) recurrence group

typedef __attribute__((ext_vector_type(4))) float f32x4;
typedef __attribute__((ext_vector_type(8))) __bf16 bf16x8;
typedef __attribute__((ext_vector_type(4))) unsigned short u16x4;
typedef __attribute__((ext_vector_type(4))) int i32x4;
typedef unsigned short u16;

static __device__ __forceinline__ u16 f2bf(float f) {
  union { float f; uint32_t u; } v; v.f = f;
  uint32_t u = v.u;
  return (u16)((u + 0x7fffu + ((u >> 16) & 1u)) >> 16);  // RNE
}

static __device__ __forceinline__ f32x4 MFMA(bf16x8 a, bf16x8 b, f32x4 c) {
  return __builtin_amdgcn_mfma_f32_16x16x32_bf16(a, b, c, 0, 0, 0);
}

// device-scope (L3-coherent) ops — bypass XCD-local caches, so no per-step flushes needed
static __device__ __forceinline__ void st_short_sc(u16* p, u16 v) {
  asm volatile("global_store_short %0, %1, off sc1" :: "v"(p), "v"((uint32_t)v) : "memory");
}
static __device__ __forceinline__ void ld_b128_sc(const u16* p, i32x4& d) {
  asm volatile("global_load_dwordx4 %0, %1, off sc1" : "=v"(d) : "v"(p) : "memory");
}

// ---------------- embedding gather: emb_x[row][e] = bf16(emb[token[row]][e]) ----------------
__global__ __launch_bounds__(256) void k_emb(const int* __restrict__ doc, const int* __restrict__ qry,
                                             const float* __restrict__ emb, u16* __restrict__ embx) {
  int i = blockIdx.x * 256 + threadIdx.x;          // 34816*96 tasks (float4 granules)
  int row = i / 96, e4 = i - row * 96;
  int tok = (row < NB * DD) ? doc[row] : qry[row - NB * DD];
  float4 v = ((const float4*)(emb + (size_t)tok * EE))[e4];
  u16x4 o; o.x = f2bf(v.x); o.y = f2bf(v.y); o.z = f2bf(v.z); o.w = f2bf(v.w);
  *(u16x4*)(embx + (size_t)row * EE + e4 * 4) = o;
}

// ---------------- fused BiGRU recurrence (R1 math, sc1 exchange + relaxed barrier) ----------------
__global__ __launch_bounds__(256) void k_rec(
    const u16* __restrict__ embx,
    const int* __restrict__ doc_lens, const int* __restrict__ q_lens,
    const float* __restrict__ w_ih_f, const float* __restrict__ w_hh_f,
    const float* __restrict__ b_ih_f, const float* __restrict__ b_hh_f,
    const float* __restrict__ w_ih_b, const float* __restrict__ w_hh_b,
    const float* __restrict__ b_ih_b, const float* __restrict__ b_hh_b,
    u16* __restrict__ doc_h, u16* __restrict__ q_h,
    u16* __restrict__ h_bc, unsigned* __restrict__ cnts) {
  __shared__ u16 wfrag[73728];       // 6 n-tiles x 24 k-steps x 64 lanes x 8 bf16 = 147456 B
  __shared__ int lensh[32];

  const int grp = blockIdx.x / NW;
  const int wg = blockIdx.x - grp * NW;
  const int corpus = grp >> 1, dir = grp & 1;
  const int T = corpus ? QQ : DD;
  const int* lens = corpus ? q_lens : doc_lens;
  const float* w_ih = dir ? w_ih_b : w_ih_f;
  const float* w_hh = dir ? w_hh_b : w_hh_f;
  const float* b_ih = dir ? b_ih_b : b_ih_f;
  const float* b_hh = dir ? b_hh_b : b_hh_f;
  u16* out = corpus ? q_h : doc_h;
  const u16* ex_base = embx + (corpus ? (size_t)NB * DD * EE : 0);
  u16* hb = h_bc + (size_t)grp * (2 * NB * HH);
  unsigned* cnt = cnts + (size_t)grp * (1056 * 16);
  const int tid = threadIdx.x;

  if (tid < 32) lensh[tid] = lens[tid];
  // pack weight slice into per-fragment LDS layout (identical to R1)
  for (int idx = tid; idx < 73728; idx += 256) {
    int nt = idx / 12288;
    int rem = idx - nt * 12288;
    int ks = rem >> 9;
    int le = rem & 511;
    int lane_ = le >> 3, i = le & 7;
    int g = nt >> 1, js_ = nt & 1;
    int colw = lane_ & 15, khiw = lane_ >> 4;
    int k = ks * 32 + khiw * 8 + i;
    int rowg = g * 384 + wg * 32 + js_ * 16 + colw;
    float v = (k < 384) ? w_ih[rowg * 384 + k] : w_hh[rowg * 384 + (k - 384)];
    wfrag[idx] = f2bf(v);
  }
  // zero own slice of broadcast buf 0 (device-scope stores)
  for (int idx = tid; idx < 1024; idx += 256) {
    int b = idx >> 5, jl_ = idx & 31;
    st_short_sc(hb + b * HH + wg * 32 + jl_, (u16)0);
  }
  asm volatile("s_waitcnt vmcnt(0)" ::: "memory");
  __syncthreads();
  if (tid == 0) {
    __hip_atomic_fetch_add(cnt, 1u, __ATOMIC_RELAXED, __HIP_MEMORY_SCOPE_AGENT);
    while (__hip_atomic_load(cnt, __ATOMIC_RELAXED, __HIP_MEMORY_SCOPE_AGENT) < (unsigned)NW)
      __builtin_amdgcn_s_sleep(1);
  }
  __syncthreads();

  const int lane = tid & 63, wv = tid >> 6;
  const int mt = wv >> 1, js = wv & 1;
  const int col = lane & 15, khi = lane >> 4;
  const int jg = wg * 32 + js * 16 + col;          // hidden dim this lane produces
  const float bias_r = b_ih[jg] + b_hh[jg];
  const float bias_z = b_ih[384 + jg] + b_hh[384 + jg];
  const float bias_in = b_ih[768 + jg];
  const float bias_hn = b_hh[768 + jg];
  const int b_x = mt * 16 + col;                   // A-fragment batch row
  const int len_x = lensh[b_x];
  const int bh0 = mt * 16 + khi * 4;               // accumulator batch base
  int len_h[4];
#pragma unroll
  for (int r = 0; r < 4; ++r) len_h[r] = lensh[bh0 + r];
  const u16* exrow = ex_base + (size_t)b_x * T * EE + khi * 8;
  u16* outp = out + (size_t)dir * HH + jg;
  f32x4 hprev{0.f, 0.f, 0.f, 0.f};                 // carried f32 state (same slot per thread as R1's h_own)

  auto trow_of = [&](int s) -> int { return dir ? ((s < len_x) ? (len_x - 1 - s) : s) : s; };
  auto load_ax = [&](bf16x8* ax, int s) {
    const u16* axp = exrow + (size_t)trow_of(s) * EE;
#pragma unroll
    for (int ks = 0; ks < 12; ++ks) ax[ks] = *(const bf16x8*)(axp + ks * 32);
  };

  bf16x8 axA[12], axB[12];
  load_ax(axA, 0);

  auto step = [&](int s, bf16x8* axc, bf16x8* axn) {
    const int p = s & 1;
    const u16* rbuf = hb + p * (NB * HH);
    u16* wbuf = hb + (p ^ 1) * (NB * HH);
    if (s + 1 < T) load_ax(axn, s + 1);            // next-x prefetch (plain cached, overlaps h latency)
    i32x4 areg[12];
    const u16* ahp = rbuf + b_x * HH + khi * 8;
#pragma unroll
    for (int ks = 0; ks < 12; ++ks) ld_b128_sc(ahp + ks * 32, areg[ks]);   // h from L3
    f32x4 acc_r{0.f, 0.f, 0.f, 0.f};
    f32x4 acc_z = acc_r, acc_nx = acc_r, acc_nh = acc_r;
#pragma unroll
    for (int ks = 0; ks < 12; ++ks) {   // x-part (K 0..383) — no h dependency, runs under h loads
      bf16x8 br = *(const bf16x8*)&wfrag[((js) * 24 + ks) * 512 + lane * 8];
      bf16x8 bz = *(const bf16x8*)&wfrag[((2 + js) * 24 + ks) * 512 + lane * 8];
      bf16x8 bn = *(const bf16x8*)&wfrag[((4 + js) * 24 + ks) * 512 + lane * 8];
      acc_r = MFMA(axc[ks], br, acc_r);
      acc_z = MFMA(axc[ks], bz, acc_z);
      acc_nx = MFMA(axc[ks], bn, acc_nx);
    }
    asm volatile("s_waitcnt vmcnt(0)" ::: "memory");
    __builtin_amdgcn_sched_barrier(0);
#pragma unroll
    for (int ks = 0; ks < 12; ++ks) {   // h-part (K 384..767)
      bf16x8 af = __builtin_bit_cast(bf16x8, areg[ks]);
      bf16x8 br = *(const bf16x8*)&wfrag[((js) * 24 + 12 + ks) * 512 + lane * 8];
      bf16x8 bz = *(const bf16x8*)&wfrag[((2 + js) * 24 + 12 + ks) * 512 + lane * 8];
      bf16x8 bn = *(const bf16x8*)&wfrag[((4 + js) * 24 + 12 + ks) * 512 + lane * 8];
      acc_r = MFMA(af, br, acc_r);
      acc_z = MFMA(af, bz, acc_z);
      acc_nh = MFMA(af, bn, acc_nh);
    }
#pragma unroll
    for (int r = 0; r < 4; ++r) {
      const int b = bh0 + r;
      float rg = 1.f / (1.f + __expf(-(acc_r[r] + bias_r)));
      float zg = 1.f / (1.f + __expf(-(acc_z[r] + bias_z)));
      float ng = tanhf(acc_nx[r] + bias_in + rg * (acc_nh[r] + bias_hn));
      float hn = (1.f - zg) * ng + zg * hprev[r];
      hprev[r] = hn;
      u16 hq = f2bf(hn);
      st_short_sc(wbuf + b * HH + jg, hq);         // device-scope h broadcast
      const int len = len_h[r];
      const int tro = dir ? ((s < len) ? (len - 1 - s) : s) : s;
      outp[((size_t)b * T + tro) * (2 * HH)] = hq; // plain store, flushed at kernel end
    }
    asm volatile("s_waitcnt vmcnt(0)" ::: "memory");
    __syncthreads();
    if (tid == 0) {
      unsigned* c = cnt + (size_t)(s + 1) * 16;
      __hip_atomic_fetch_add(c, 1u, __ATOMIC_RELAXED, __HIP_MEMORY_SCOPE_AGENT);
      while (__hip_atomic_load(c, __ATOMIC_RELAXED, __HIP_MEMORY_SCOPE_AGENT) < (unsigned)NW)
        __builtin_amdgcn_s_sleep(1);
    }
    __syncthreads();
  };

  for (int s = 0; s < T; s += 2) {
    step(s, axA, axB);
    step(s + 1, axB, axA);
  }
}

// ---------------- scores + row (q-axis) stats ----------------
__global__ __launch_bounds__(256) void k_scores(
    const u16* __restrict__ doc_h, const u16* __restrict__ q_h,
    const int* __restrict__ doc_lens, const int* __restrict__ q_lens,
    float* __restrict__ SM, float* __restrict__ rowmax, float* __restrict__ rowsum) {
  const int b = blockIdx.x >> 4, dblk = blockIdx.x & 15;
  const int tid = threadIdx.x, lane = tid & 63, wv = tid >> 6;
  const int col = lane & 15, khi = lane >> 4;
  const int dlen = doc_lens[b], qlen = q_lens[b];
  const u16* dp = doc_h + ((size_t)(b * DD + dblk * 64 + wv * 16 + col)) * (2 * HH) + khi * 8;
  const u16* qp = q_h + (size_t)b * QQ * (2 * HH);
  f32x4 acc[4];
#pragma unroll
  for (int nt = 0; nt < 4; ++nt) acc[nt] = f32x4{0.f, 0.f, 0.f, 0.f};
  for (int ks = 0; ks < 24; ++ks) {
    bf16x8 av = *(const bf16x8*)(dp + ks * 32);
#pragma unroll
    for (int nt = 0; nt < 4; ++nt) {
      bf16x8 bv = *(const bf16x8*)(qp + (size_t)(nt * 16 + col) * (2 * HH) + ks * 32 + khi * 8);
      acc[nt] = MFMA(av, bv, acc[nt]);
    }
  }
  const int d0 = dblk * 64 + wv * 16 + khi * 4;
  float* smb = SM + (size_t)b * DD * QQ;
#pragma unroll
  for (int r = 0; r < 4; ++r) {
    const int d = d0 + r;
    const bool dv = d < dlen;
    float v[4];
#pragma unroll
    for (int nt = 0; nt < 4; ++nt) {
      const int q = nt * 16 + col;
      v[nt] = (dv && q < qlen) ? acc[nt][r] : 0.f;
      smb[(size_t)d * QQ + q] = v[nt];
    }
    float mx = fmaxf(fmaxf(v[0], v[1]), fmaxf(v[2], v[3]));
#pragma unroll
    for (int off = 1; off < 16; off <<= 1) mx = fmaxf(mx, __shfl_xor(mx, off, 64));
    float sm = 0.f;
#pragma unroll
    for (int nt = 0; nt < 4; ++nt) {
      const int q = nt * 16 + col;
      if (dv && q < qlen) sm += __expf(v[nt] - mx);
    }
#pragma unroll
    for (int off = 1; off < 16; off <<= 1) sm += __shfl_xor(sm, off, 64);
    if (col == 0) { rowmax[b * DD + d] = mx; rowsum[b * DD + d] = sm; }
  }
}

// ---------------- column (d-axis) stats + beta_aver ----------------
__global__ __launch_bounds__(256) void k_cols(
    const float* __restrict__ SM, const float* __restrict__ rowmax, const float* __restrict__ rowsum,
    const int* __restrict__ doc_lens, const int* __restrict__ q_lens,
    float* __restrict__ colmax, float* __restrict__ colsum, float* __restrict__ bav) {
  const int b = blockIdx.x, tid = threadIdx.x;
  const int q = tid & 63, dg = tid >> 6;
  __shared__ float red[4][64];
  __shared__ float cmx[64];
  const float* smb = SM + (size_t)b * DD * QQ;
  float cm = -3.0e38f;
  for (int d = dg; d < DD; d += 4) cm = fmaxf(cm, smb[(size_t)d * QQ + q]);
  red[dg][q] = cm;
  __syncthreads();
  if (tid < 64) cmx[tid] = fmaxf(fmaxf(red[0][tid], red[1][tid]), fmaxf(red[2][tid], red[3][tid]));
  __syncthreads();
  const int dlen = doc_lens[b];
  const bool qv = q < q_lens[b];
  const float cmq = cmx[q];
  float cs = 0.f, ba = 0.f;
  for (int d = dg; d < DD; d += 4) {
    if (qv && d < dlen) {
      float v = smb[(size_t)d * QQ + q];
      cs += __expf(v - cmq);
      ba += __expf(v - rowmax[b * DD + d]) / (rowsum[b * DD + d] + EPSV);
    }
  }
  __syncthreads();
  red[dg][q] = cs;
  __syncthreads();
  float cst = 0.f;
  if (tid < 64) cst = red[0][tid] + red[1][tid] + red[2][tid] + red[3][tid];
  __syncthreads();
  red[dg][q] = ba;
  __syncthreads();
  if (tid < 64) {
    float bat = red[0][tid] + red[1][tid] + red[2][tid] + red[3][tid];
    colmax[b * QQ + tid] = cmx[tid];
    colsum[b * QQ + tid] = cst;
    bav[b * QQ + tid] = bat / (float)dlen;
  }
}

// ---------------- s = alpha @ beta_aver, probs, vocab scatter ----------------
__global__ __launch_bounds__(256) void k_s(
    const float* __restrict__ SM, const float* __restrict__ colmax, const float* __restrict__ colsum,
    const float* __restrict__ bav, const int* __restrict__ doc_lens, const int* __restrict__ q_lens,
    const int* __restrict__ documents, const int* __restrict__ answers,
    float* __restrict__ sc, float* __restrict__ cnt_tok, float* __restrict__ dout) {
  const int b = blockIdx.x >> 2, dblk = blockIdx.x & 3;
  const int tid = threadIdx.x;
  __shared__ float cm[64], cs[64], bv[64];
  __shared__ int qm[64];
  if (tid < 64) {
    cm[tid] = colmax[b * QQ + tid];
    cs[tid] = colsum[b * QQ + tid];
    bv[tid] = bav[b * QQ + tid];
    qm[tid] = (tid < q_lens[b]) ? 1 : 0;
  }
  __syncthreads();
  const int d = dblk * 256 + tid;
  const bool dv = d < doc_lens[b];
  const float* smr = SM + ((size_t)b * DD + d) * QQ;
  float sd = 0.f;
#pragma unroll
  for (int q = 0; q < 64; ++q) {
    float e = (dv && qm[q]) ? __expf(smr[q] - cm[q]) : 0.f;
    sd += e / (cs[q] + EPSV) * bv[q];
  }
  const int tok = documents[b * DD + d];
  if (tok == answers[b]) atomicAdd(&dout[b], sd);
  if (dv) {
    atomicAdd(&sc[(size_t)b * 50001 + tok], sd);
    atomicAdd(&cnt_tok[(size_t)b * 50001 + tok], 1.0f);
  }
}

// ---------------- first-max argmax over vocab ----------------
__global__ __launch_bounds__(256) void k_pred(
    const float* __restrict__ sc, const float* __restrict__ cnt_tok, float* __restrict__ dout) {
  const int b = blockIdx.x, tid = threadIdx.x;
  __shared__ float bvs[256];
  __shared__ int bis[256];
  float bvv = -3.0e38f;
  int bii = 0x7fffffff;
  for (int i = tid; i < 50001; i += 256) {
    if (cnt_tok[(size_t)b * 50001 + i] > 0.f) {
      float v = sc[(size_t)b * 50001 + i];
      if (v > bvv) { bvv = v; bii = i; }
    }
  }
  bvs[tid] = bvv;
  bis[tid] = bii;
  __syncthreads();
  for (int st = 128; st > 0; st >>= 1) {
    if (tid < st) {
      float v2 = bvs[tid + st];
      int i2 = bis[tid + st];
      if (v2 > bvs[tid] || (v2 == bvs[tid] && i2 < bis[tid])) { bvs[tid] = v2; bis[tid] = i2; }
    }
    __syncthreads();
  }
  if (tid == 0) dout[32 + b] = (float)bis[0];
}

extern "C" void kernel_launch(void* const* d_in, const int* in_sizes, int n_in,
                              void* d_out, int out_size, void* d_ws, size_t ws_size,
                              hipStream_t stream) {
  const int* documents = (const int*)d_in[0];
  const int* doc_lens = (const int*)d_in[1];
  const int* querys = (const int*)d_in[3];
  const int* query_lens = (const int*)d_in[4];
  const int* answers = (const int*)d_in[6];
  const float* emb = (const float*)d_in[7];
  const float* w_ih_f = (const float*)d_in[8];
  const float* w_hh_f = (const float*)d_in[9];
  const float* b_ih_f = (const float*)d_in[10];
  const float* b_hh_f = (const float*)d_in[11];
  const float* w_ih_b = (const float*)d_in[12];
  const float* w_hh_b = (const float*)d_in[13];
  const float* b_ih_b = (const float*)d_in[14];
  const float* b_hh_b = (const float*)d_in[15];
  float* dout = (float*)d_out;
  char* ws = (char*)d_ws;

  size_t o = 0;
  auto alloc = [&](size_t bytes) { size_t r = o; o += (bytes + 255) & ~(size_t)255; return r; };
  size_t o_embx = alloc((size_t)34816 * 384 * 2);
  size_t o_doch = alloc((size_t)NB * DD * 768 * 2);
  size_t o_qh   = alloc((size_t)NB * QQ * 768 * 2);
  size_t o_hbc  = alloc((size_t)4 * 2 * NB * HH * 2);
  size_t o_cnt  = alloc((size_t)4 * 1056 * 16 * 4);
  size_t o_SM   = alloc((size_t)NB * DD * QQ * 4);
  size_t o_rmax = alloc((size_t)NB * DD * 4);
  size_t o_rsum = alloc((size_t)NB * DD * 4);
  size_t o_cmax = alloc((size_t)NB * QQ * 4);
  size_t o_csum = alloc((size_t)NB * QQ * 4);
  size_t o_bav  = alloc((size_t)NB * QQ * 4);
  size_t o_sc   = alloc((size_t)NB * 50001 * 4);
  size_t o_ctk  = alloc((size_t)NB * 50001 * 4);
  (void)ws_size; (void)in_sizes; (void)n_in; (void)out_size;

  hipMemsetAsync(ws + o_cnt, 0, (size_t)4 * 1056 * 16 * 4, stream);
  hipMemsetAsync(ws + o_sc, 0, (o_ctk - o_sc) + (size_t)NB * 50001 * 4, stream);
  hipMemsetAsync(d_out, 0, 64 * sizeof(float), stream);

  k_emb<<<13056, 256, 0, stream>>>(documents, querys, emb, (u16*)(ws + o_embx));
  k_rec<<<48, 256, 0, stream>>>((u16*)(ws + o_embx), doc_lens, query_lens,
                                w_ih_f, w_hh_f, b_ih_f, b_hh_f,
                                w_ih_b, w_hh_b, b_ih_b, b_hh_b,
                                (u16*)(ws + o_doch), (u16*)(ws + o_qh),
                                (u16*)(ws + o_hbc), (unsigned*)(ws + o_cnt));
  k_scores<<<512, 256, 0, stream>>>((u16*)(ws + o_doch), (u16*)(ws + o_qh), doc_lens, query_lens,
                                    (float*)(ws + o_SM), (float*)(ws + o_rmax), (float*)(ws + o_rsum));
  k_cols<<<32, 256, 0, stream>>>((float*)(ws + o_SM), (float*)(ws + o_rmax), (float*)(ws + o_rsum),
                                 doc_lens, query_lens,
                                 (float*)(ws + o_cmax), (float*)(ws + o_csum), (float*)(ws + o_bav));
  k_s<<<128, 256, 0, stream>>>((float*)(ws + o_SM), (float*)(ws + o_cmax), (float*)(ws + o_csum),
                               (float*)(ws + o_bav), doc_lens, query_lens, documents, answers,
                               (float*)(ws + o_sc), (float*)(ws + o_ctk), dout);
  k_pred<<<32, 256, 0, stream>>>((float*)(ws + o_sc), (float*)(ws + o_ctk), dout);
}